// Round 17
// baseline (732.987 us; speedup 1.0000x reference)
//
#include <hip/hip_runtime.h>
#include <hip/hip_bf16.h>
#include <cmath>

#define TT 2048
#define HID 2048
#define NHEADS 16
#define HDIM 128
#define NEXP 8
#define INTERD 1024
#define EPSV 1e-5f

typedef short bf16x8 __attribute__((ext_vector_type(8)));
typedef float f32x4 __attribute__((ext_vector_type(4)));

__device__ __forceinline__ unsigned short f2bf(float f) {
    unsigned int u = __builtin_bit_cast(unsigned int, f);
    unsigned int r = (u + 0x7FFFu + ((u >> 16) & 1u)) >> 16;
    return (unsigned short)r;
}
__device__ __forceinline__ float bf2f(unsigned short h) {
    return __builtin_bit_cast(float, (unsigned int)h << 16);
}

__device__ __forceinline__ void gll16(const void* g, void* l) {
    __builtin_amdgcn_global_load_lds((const __attribute__((address_space(1))) void*)g,
                                     (__attribute__((address_space(3))) void*)l, 16, 0, 0);
}

__device__ __forceinline__ float block_reduce_sum_256(float v, float* red) {
    const int tid = threadIdx.x;
    red[tid] = v;
    __syncthreads();
    for (int s = 128; s > 0; s >>= 1) {
        if (tid < s) red[tid] += red[tid + s];
        __syncthreads();
    }
    float r = red[0];
    __syncthreads();
    return r;
}

// ---------- f32 -> (hi, lo) bf16 planes ----------
__global__ __launch_bounds__(256) void split_f32k(const float* __restrict__ x,
                                                  unsigned short* __restrict__ hi,
                                                  unsigned short* __restrict__ lo, int n4) {
    int i = blockIdx.x * 256 + threadIdx.x;
    if (i >= n4) return;
    float4 v = reinterpret_cast<const float4*>(x)[i];
    float xs[4] = {v.x, v.y, v.z, v.w};
    unsigned short hs[4], ls[4];
#pragma unroll
    for (int u = 0; u < 4; ++u) {
        hs[u] = f2bf(xs[u]);
        ls[u] = f2bf(xs[u] - bf2f(hs[u]));
    }
    uint2 hp; hp.x = hs[0] | ((unsigned)hs[1] << 16); hp.y = hs[2] | ((unsigned)hs[3] << 16);
    uint2 lp; lp.x = ls[0] | ((unsigned)ls[1] << 16); lp.y = ls[2] | ((unsigned)ls[3] << 16);
    *reinterpret_cast<uint2*>(hi + (size_t)i * 4) = hp;
    *reinterpret_cast<uint2*>(lo + (size_t)i * 4) = lp;
}

// ===================== split-precision MFMA GEMM, pre-split operands, dbuf + counted vmcnt =========
// BK=32, double-buffered 2x32KB LDS. Conflict-free swizzle: slot s of row r holds k-group
// s ^ ((r>>1)&3)  [64B rows alias banks every 2 rows].
#define GSTAGE(BUF, K0)                                                             \
    {                                                                               \
        char* base_ = (char*)Smem + (BUF) * 32768;                                  \
        _Pragma("unroll")                                                           \
        for (int i_ = 0; i_ < 2; ++i_) {                                            \
            int c_ = tid + i_ * 256;                                                \
            int r_ = c_ >> 2, s_ = c_ & 3;                                          \
            int ko_ = (K0) + (((s_ ^ ((r_ >> 1) & 3)) & 3) << 3);                   \
            gll16(Ah + (size_t)(m0 + r_) * lda + ko_, base_ + c_ * 16);             \
            gll16(Al + (size_t)(m0 + r_) * lda + ko_, base_ + 8192 + c_ * 16);      \
            gll16(Bh + (size_t)(n0 + r_) * K + ko_, base_ + 16384 + c_ * 16);       \
            gll16(Bl + (size_t)(n0 + r_) * K + ko_, base_ + 24576 + c_ * 16);       \
        }                                                                           \
    }

__global__ __launch_bounds__(256) void gemm_sp(const unsigned short* __restrict__ Ah,
                                               const unsigned short* __restrict__ Al,
                                               const unsigned short* __restrict__ Bh,
                                               const unsigned short* __restrict__ Bl,
                                               float* __restrict__ C, int N, int K, int lda) {
    // bijective XCD-aware block swizzle (T1)
    const int nbx = gridDim.x;
    const int nwg = nbx * gridDim.y;
    const int orig = blockIdx.y * nbx + blockIdx.x;
    const int qq = nwg >> 3, rr = nwg & 7;
    const int xcd = orig & 7, loc = orig >> 3;
    const int wgid = (xcd < rr ? xcd * (qq + 1) : rr * (qq + 1) + (xcd - rr) * qq) + loc;
    const int m0 = (wgid / nbx) * 128, n0 = (wgid % nbx) * 128;

    __shared__ __align__(16) unsigned short Smem[2 * 4 * 128 * 32];  // 64 KB
    const int tid = threadIdx.x;
    const int w = tid >> 6, l = tid & 63;
    const int lr = l & 15, lg = l >> 4;
    const int wm = w >> 1, wn = w & 1;

    f32x4 acc[4][4];
#pragma unroll
    for (int i = 0; i < 4; ++i)
#pragma unroll
        for (int j = 0; j < 4; ++j) acc[i][j] = f32x4{0.f, 0.f, 0.f, 0.f};

    const int nks = K >> 5;
    GSTAGE(0, 0);
    int cur = 0;
    for (int ks = 0; ks < nks; ++ks) {
        if (ks + 1 < nks) {
            GSTAGE(cur ^ 1, (ks + 1) << 5);
            asm volatile("s_waitcnt vmcnt(8)" ::: "memory");
        } else {
            asm volatile("s_waitcnt vmcnt(0)" ::: "memory");
        }
        __builtin_amdgcn_s_barrier();
        __builtin_amdgcn_sched_barrier(0);
        char* bb = (char*)Smem + cur * 32768;
        bf16x8 bhf[4], blf[4];
#pragma unroll
        for (int nt = 0; nt < 4; ++nt) {
            int row = wn * 64 + nt * 16 + lr;
            int off = row * 64 + (((lg ^ ((row >> 1) & 3)) & 3) << 4);
            bhf[nt] = *reinterpret_cast<const bf16x8*>(bb + 16384 + off);
            blf[nt] = *reinterpret_cast<const bf16x8*>(bb + 24576 + off);
        }
        __builtin_amdgcn_s_setprio(1);
#pragma unroll
        for (int mt = 0; mt < 4; ++mt) {
            int row = wm * 64 + mt * 16 + lr;
            int off = row * 64 + (((lg ^ ((row >> 1) & 3)) & 3) << 4);
            bf16x8 ahf = *reinterpret_cast<const bf16x8*>(bb + off);
            bf16x8 alf = *reinterpret_cast<const bf16x8*>(bb + 8192 + off);
#pragma unroll
            for (int nt = 0; nt < 4; ++nt) {
                acc[mt][nt] = __builtin_amdgcn_mfma_f32_16x16x32_bf16(ahf, bhf[nt], acc[mt][nt], 0, 0, 0);
                acc[mt][nt] = __builtin_amdgcn_mfma_f32_16x16x32_bf16(ahf, blf[nt], acc[mt][nt], 0, 0, 0);
                acc[mt][nt] = __builtin_amdgcn_mfma_f32_16x16x32_bf16(alf, bhf[nt], acc[mt][nt], 0, 0, 0);
            }
        }
        __builtin_amdgcn_s_setprio(0);
        asm volatile("s_waitcnt lgkmcnt(0)" ::: "memory");
        __builtin_amdgcn_s_barrier();
        __builtin_amdgcn_sched_barrier(0);
        cur ^= 1;
    }
#pragma unroll
    for (int mt = 0; mt < 4; ++mt) {
#pragma unroll
        for (int r = 0; r < 4; ++r) {
            size_t crow = (size_t)(m0 + wm * 64 + mt * 16 + lg * 4 + r) * N;
#pragma unroll
            for (int nt = 0; nt < 4; ++nt)
                C[crow + n0 + wn * 64 + nt * 16 + lr] = acc[mt][nt][r];
        }
    }
}

// ===================== fused MoE gate+up GEMM: A bf16 (gather, staged once), dual acc, silu fused ===
__global__ __launch_bounds__(256) void gemm_gu(const unsigned short* __restrict__ Abf,
                                               const float* __restrict__ Bg,
                                               const float* __restrict__ Bu,
                                               unsigned short* __restrict__ Hout,
                                               int N, int K, int lda,
                                               size_t strideB,
                                               const int* __restrict__ gather,
                                               const int* __restrict__ offs,
                                               const int* __restrict__ counts) {
    const int e = blockIdx.z;
    const int cnt = counts[e];
    const int base = offs[e];
    const int m0 = blockIdx.y * 128;
    if (m0 >= cnt) return;
    const int n0 = blockIdx.x * 128;
    const float* Bgp = Bg + (size_t)e * strideB;
    const float* Bup = Bu + (size_t)e * strideB;

    __shared__ unsigned short smA[128 * 64];
    __shared__ unsigned short smG[128 * 64];
    __shared__ unsigned short smU[128 * 64];
    __shared__ int rowsA[128];
    const int tid = threadIdx.x;
    if (tid < 128) {
        int rr = min(m0 + tid, cnt - 1);
        rowsA[tid] = gather[base + rr];
    }
    __syncthreads();

    const int w = tid >> 6, l = tid & 63;
    const int lr = l & 15, lg = l >> 4;
    const int wm = w >> 1, wn = w & 1;
    char* sA = (char*)smA;
    char* sG = (char*)smG;
    char* sU = (char*)smU;

    f32x4 accg[4][4], accu[4][4];
#pragma unroll
    for (int i = 0; i < 4; ++i)
#pragma unroll
        for (int j = 0; j < 4; ++j) { accg[i][j] = f32x4{0.f, 0.f, 0.f, 0.f}; accu[i][j] = f32x4{0.f, 0.f, 0.f, 0.f}; }

    for (int k0 = 0; k0 < K; k0 += 64) {
        // A: bf16, 128 rows x 8 chunks of 16B (128B/row)
#pragma unroll
        for (int i = 0; i < 4; ++i) {
            int slot = tid + i * 256;
            int r = slot >> 3, sg = slot & 7;
            uint4 v = *reinterpret_cast<const uint4*>(&Abf[(size_t)rowsA[r] * lda + k0 + sg * 8]);
            *reinterpret_cast<uint4*>(sA + r * 128 + ((sg * 16) ^ ((r & 7) << 4))) = v;
        }
        // G and U: f32 stage-convert
#pragma unroll
        for (int i = 0; i < 8; ++i) {
            int slot = tid + i * 256;
            int r = slot >> 4, kq = slot & 15;
            float4 gv = *reinterpret_cast<const float4*>(&Bgp[(size_t)(n0 + r) * K + k0 + kq * 4]);
            float4 uv = *reinterpret_cast<const float4*>(&Bup[(size_t)(n0 + r) * K + k0 + kq * 4]);
            uint2 pg, pu;
            pg.x = (unsigned)f2bf(gv.x) | ((unsigned)f2bf(gv.y) << 16);
            pg.y = (unsigned)f2bf(gv.z) | ((unsigned)f2bf(gv.w) << 16);
            pu.x = (unsigned)f2bf(uv.x) | ((unsigned)f2bf(uv.y) << 16);
            pu.y = (unsigned)f2bf(uv.z) | ((unsigned)f2bf(uv.w) << 16);
            int off = r * 128 + ((kq * 8) ^ ((r & 7) << 4));
            *reinterpret_cast<uint2*>(sG + off) = pg;
            *reinterpret_cast<uint2*>(sU + off) = pu;
        }
        __syncthreads();
#pragma unroll
        for (int kk = 0; kk < 2; ++kk) {
            bf16x8 af[4], bgf[4], buf_[4];
#pragma unroll
            for (int mt = 0; mt < 4; ++mt) {
                int row = wm * 64 + mt * 16 + lr;
                af[mt] = *reinterpret_cast<const bf16x8*>(sA + row * 128 + ((kk * 64 + lg * 16) ^ ((row & 7) << 4)));
            }
#pragma unroll
            for (int nt = 0; nt < 4; ++nt) {
                int row = wn * 64 + nt * 16 + lr;
                int off = row * 128 + ((kk * 64 + lg * 16) ^ ((row & 7) << 4));
                bgf[nt] = *reinterpret_cast<const bf16x8*>(sG + off);
                buf_[nt] = *reinterpret_cast<const bf16x8*>(sU + off);
            }
            __builtin_amdgcn_s_setprio(1);
#pragma unroll
            for (int mt = 0; mt < 4; ++mt)
#pragma unroll
                for (int nt = 0; nt < 4; ++nt) {
                    accg[mt][nt] = __builtin_amdgcn_mfma_f32_16x16x32_bf16(af[mt], bgf[nt], accg[mt][nt], 0, 0, 0);
                    accu[mt][nt] = __builtin_amdgcn_mfma_f32_16x16x32_bf16(af[mt], buf_[nt], accu[mt][nt], 0, 0, 0);
                }
            __builtin_amdgcn_s_setprio(0);
        }
        __syncthreads();
    }
#pragma unroll
    for (int mt = 0; mt < 4; ++mt) {
#pragma unroll
        for (int r = 0; r < 4; ++r) {
            int rowl = wm * 64 + mt * 16 + lg * 4 + r;
            if (m0 + rowl < cnt) {
                size_t crow = (size_t)(base + m0 + rowl) * N;
#pragma unroll
                for (int nt = 0; nt < 4; ++nt) {
                    size_t idx = crow + n0 + wn * 64 + nt * 16 + lr;
                    float g = accg[mt][nt][r];
                    float u = accu[mt][nt][r];
                    Hout[idx] = f2bf(g / (1.f + expf(-g)) * u);
                }
            }
        }
    }
}

// ===================== MoE down GEMM: A bf16 (packed), B f32 stage-convert ==========================
__global__ __launch_bounds__(256) void gemm_moe_down(const unsigned short* __restrict__ Abf,
                                                     const float* __restrict__ B,
                                                     float* __restrict__ C,
                                                     int N, int K, int lda,
                                                     size_t strideB,
                                                     const int* __restrict__ offs,
                                                     const int* __restrict__ counts) {
    const int e = blockIdx.z;
    const int cnt = counts[e];
    const int base = offs[e];
    const int m0 = blockIdx.y * 128;
    if (m0 >= cnt) return;
    const int n0 = blockIdx.x * 128;
    const float* Bp = B + (size_t)e * strideB;

    __shared__ unsigned short smA[128 * 64];
    __shared__ unsigned short smB[128 * 64];
    const int tid = threadIdx.x;
    const int w = tid >> 6, l = tid & 63;
    const int lr = l & 15, lg = l >> 4;
    const int wm = w >> 1, wn = w & 1;
    char* sA = (char*)smA;
    char* sB = (char*)smB;

    f32x4 acc[4][4];
#pragma unroll
    for (int i = 0; i < 4; ++i)
#pragma unroll
        for (int j = 0; j < 4; ++j) acc[i][j] = f32x4{0.f, 0.f, 0.f, 0.f};

    for (int k0 = 0; k0 < K; k0 += 64) {
#pragma unroll
        for (int i = 0; i < 4; ++i) {
            int slot = tid + i * 256;
            int r = slot >> 3, sg = slot & 7;
            int arow = base + min(m0 + r, cnt - 1);
            uint4 v = *reinterpret_cast<const uint4*>(&Abf[(size_t)arow * lda + k0 + sg * 8]);
            *reinterpret_cast<uint4*>(sA + r * 128 + ((sg * 16) ^ ((r & 7) << 4))) = v;
        }
#pragma unroll
        for (int i = 0; i < 8; ++i) {
            int slot = tid + i * 256;
            int r = slot >> 4, kq = slot & 15;
            float4 bv = *reinterpret_cast<const float4*>(&Bp[(size_t)(n0 + r) * K + k0 + kq * 4]);
            uint2 pk;
            pk.x = (unsigned)f2bf(bv.x) | ((unsigned)f2bf(bv.y) << 16);
            pk.y = (unsigned)f2bf(bv.z) | ((unsigned)f2bf(bv.w) << 16);
            *reinterpret_cast<uint2*>(sB + r * 128 + ((kq * 8) ^ ((r & 7) << 4))) = pk;
        }
        __syncthreads();
#pragma unroll
        for (int kk = 0; kk < 2; ++kk) {
            bf16x8 af[4], bfr[4];
#pragma unroll
            for (int mt = 0; mt < 4; ++mt) {
                int row = wm * 64 + mt * 16 + lr;
                af[mt] = *reinterpret_cast<const bf16x8*>(sA + row * 128 + ((kk * 64 + lg * 16) ^ ((row & 7) << 4)));
            }
#pragma unroll
            for (int nt = 0; nt < 4; ++nt) {
                int row = wn * 64 + nt * 16 + lr;
                bfr[nt] = *reinterpret_cast<const bf16x8*>(sB + row * 128 + ((kk * 64 + lg * 16) ^ ((row & 7) << 4)));
            }
#pragma unroll
            for (int mt = 0; mt < 4; ++mt)
#pragma unroll
                for (int nt = 0; nt < 4; ++nt)
                    acc[mt][nt] = __builtin_amdgcn_mfma_f32_16x16x32_bf16(af[mt], bfr[nt], acc[mt][nt], 0, 0, 0);
        }
        __syncthreads();
    }
#pragma unroll
    for (int mt = 0; mt < 4; ++mt) {
#pragma unroll
        for (int r = 0; r < 4; ++r) {
            int rowl = wm * 64 + mt * 16 + lg * 4 + r;
            if (m0 + rowl < cnt) {
                size_t crow = (size_t)(base + m0 + rowl) * N;
#pragma unroll
                for (int nt = 0; nt < 4; ++nt)
                    C[crow + n0 + wn * 64 + nt * 16 + lr] = acc[mt][nt][r];
            }
        }
    }
}

// ===================== flat-2048 RMSNorm + NeoX RoPE -> in-place hi/lo bf16 split =====================
__global__ __launch_bounds__(256) void qknorm_rope_split(float* __restrict__ qkv,
                                                         const float* __restrict__ qw,
                                                         const float* __restrict__ kw,
                                                         const int* __restrict__ pos) {
    __shared__ float xbuf[2048];
    __shared__ float red[256];
    const int t = blockIdx.x, tid = threadIdx.x;
    unsigned short* row16 = (unsigned short*)(qkv + (size_t)t * 6144);
    const float pf = (float)pos[t];
    float vreg[8];
    const float* vsrc = qkv + (size_t)t * 6144 + 4096;
#pragma unroll
    for (int i = 0; i < 8; ++i) vreg[i] = vsrc[tid + i * 256];
    __syncthreads();
#pragma unroll
    for (int i = 0; i < 8; ++i) {
        int d = tid + i * 256;
        unsigned short hi = f2bf(vreg[i]);
        row16[8192 + d] = hi;
        row16[10240 + d] = f2bf(vreg[i] - bf2f(hi));
    }
    for (int part = 0; part < 2; ++part) {
        const float* x = qkv + (size_t)t * 6144 + part * 2048;
        const float* wn = part ? kw : qw;
        const int sbase = part ? 4096 : 0;
        const float outscale = part ? 1.0f : 0.08838834764831845f;
        float s = 0.f;
#pragma unroll
        for (int i = 0; i < 8; ++i) {
            int d = tid + i * 256;
            float v = x[d];
            xbuf[d] = v;
            s = fmaf(v, v, s);
        }
        float tot = block_reduce_sum_256(s, red);
        float scale = rsqrtf(tot * (1.f / HID) + EPSV);
#pragma unroll
        for (int p = tid; p < 1024; p += 256) {
            int hh = p >> 6, j = p & 63;
            int i1 = hh * 128 + j, i2 = i1 + 64;
            float x1 = xbuf[i1] * scale * wn[i1];
            float x2 = xbuf[i2] * scale * wn[i2];
            float invf = expf(-(float)j * 0.14391156831212787f);
            float ang = pf * invf;
            float sn, cs;
            sincosf(ang, &sn, &cs);
            float o1 = (x1 * cs - x2 * sn) * outscale;
            float o2 = (x2 * cs + x1 * sn) * outscale;
            unsigned short h1_ = f2bf(o1);
            row16[sbase + i1] = h1_;
            row16[sbase + 2048 + i1] = f2bf(o1 - bf2f(h1_));
            unsigned short h2_ = f2bf(o2);
            row16[sbase + i2] = h2_;
            row16[sbase + 2048 + i2] = f2bf(o2 - bf2f(h2_));
        }
        __syncthreads();
    }
}

// ===================== K/V prep: per (head, chunk) blocks, LDS-image layouts =====================
__global__ __launch_bounds__(256) void kvprep(const unsigned short* __restrict__ qkv16,
                                              unsigned short* __restrict__ kt,
                                              unsigned short* __restrict__ vt) {
    const int C = blockIdx.x;
    const int h = blockIdx.y;
    const int tid = threadIdx.x;
#pragma unroll
    for (int p = 0; p < 2; ++p) {
#pragma unroll
        for (int i = 0; i < 4; ++i) {
            int slot = tid + i * 256;
            int r = slot >> 4, sg = slot & 15;
            uint4 v = *reinterpret_cast<const uint4*>(
                qkv16 + (size_t)(C * 64 + r) * 12288 + 4096 + p * 2048 + h * 128 + (sg ^ (r & 7)) * 8);
            *reinterpret_cast<uint4*>(kt + (size_t)(h * 32 + C) * 16384 + p * 8192 + slot * 8) = v;
        }
    }
    __shared__ unsigned short tile[64 * 128];
    char* tb = (char*)tile;
    for (int p = 0; p < 2; ++p) {
#pragma unroll
        for (int i = 0; i < 4; ++i) {
            int c = tid + i * 256;
            int r = c >> 4, dseg = c & 15;
            uint4 v = *reinterpret_cast<const uint4*>(
                qkv16 + (size_t)(C * 64 + r) * 12288 + 8192 + p * 2048 + h * 128 + dseg * 8);
            int swz = dseg ^ (r & 7) ^ (r >> 3);
            *reinterpret_cast<uint4*>(tb + r * 256 + swz * 16) = v;
        }
        __syncthreads();
        unsigned short* ob = vt + (size_t)(h * 32 + C) * 16384 + p * 8192;
#pragma unroll
        for (int i = 0; i < 4; ++i) {
            int c = tid + i * 256;
            int d = c >> 3, j = c & 7;
            unsigned short tmp[8];
#pragma unroll
            for (int u = 0; u < 8; ++u) {
                int s = 8 * j + u;
                int swz = (d >> 3) ^ (s & 7) ^ (s >> 3);
                tmp[u] = *reinterpret_cast<const unsigned short*>(tb + s * 256 + swz * 16 + (d & 7) * 2);
            }
            *reinterpret_cast<uint4*>(ob + (size_t)d * 64 + ((j ^ (d & 7)) * 8)) =
                *reinterpret_cast<const uint4*>(tmp);
        }
        __syncthreads();
    }
}

// stage one 64-key chunk (K hi/lo + V hi/lo = 64KB) direct to LDS: 16 x global_load_lds
#define STAGE1(CIDX)                                                                   \
    {                                                                                  \
        const unsigned short* kb_ = kt + (size_t)(h * 32 + (CIDX)) * 16384;            \
        const unsigned short* vb_ = vt + (size_t)(h * 32 + (CIDX)) * 16384;            \
        _Pragma("unroll")                                                              \
        for (int p_ = 0; p_ < 2; ++p_) {                                               \
            _Pragma("unroll")                                                          \
            for (int i_ = 0; i_ < 4; ++i_) {                                           \
                int slot_ = tid + i_ * 256;                                            \
                gll16(kb_ + p_ * 8192 + slot_ * 8, kvb + p_ * 16384 + slot_ * 16);     \
                gll16(vb_ + p_ * 8192 + slot_ * 8, kvb + 32768 + p_ * 16384 + slot_ * 16); \
            }                                                                          \
        }                                                                              \
    }

// ===================== split-precision MFMA flash attention (80KB LDS -> 2 blocks/CU) ==============
__global__ __launch_bounds__(256) void attn_mfma(const unsigned short* __restrict__ qkv16,
                                                 const unsigned short* __restrict__ kt,
                                                 const unsigned short* __restrict__ vt,
                                                 unsigned short* __restrict__ oh,
                                                 unsigned short* __restrict__ ol) {
    const int g = blockIdx.x;
    const int rank = (g < 256) ? g : 767 - g;
    const int h = rank & 15;
    const int t0 = (31 - (rank >> 4)) * 64;
    const int tid = threadIdx.x;
    const int w = tid >> 6, l = tid & 63;
    const int lr = l & 15, lg = l >> 4;
    const size_t RS = 12288;
    __shared__ __align__(16) unsigned short KVs[32768];
    __shared__ unsigned short Ps[4][2 * 16 * 64];
    char* kvb = (char*)KVs;
    char* PsB = (char*)(Ps[w]);

    bf16x8 qh[4], ql[4];
    {
        const unsigned short* qp = qkv16 + (size_t)(t0 + w * 16 + lr) * RS + h * 128 + lg * 8;
#pragma unroll
        for (int kk = 0; kk < 4; ++kk) {
            qh[kk] = *reinterpret_cast<const bf16x8*>(qp + kk * 32);
            ql[kk] = *reinterpret_cast<const bf16x8*>(qp + 2048 + kk * 32);
        }
    }
    f32x4 oacc[8];
#pragma unroll
    for (int dt = 0; dt < 8; ++dt) oacc[dt] = f32x4{0.f, 0.f, 0.f, 0.f};
    float mrun[4] = {-INFINITY, -INFINITY, -INFINITY, -INFINITY};
    float lrun[4] = {0.f, 0.f, 0.f, 0.f};

    for (int s0 = 0; s0 <= t0; s0 += 64) {
        STAGE1(s0 >> 6);
        __syncthreads();
        char* KsB = kvb;
        char* VtB = kvb + 32768;

        f32x4 sc[4];
#pragma unroll
        for (int nt = 0; nt < 4; ++nt) sc[nt] = f32x4{0.f, 0.f, 0.f, 0.f};
        __builtin_amdgcn_s_setprio(1);
#pragma unroll
        for (int kk = 0; kk < 4; ++kk) {
#pragma unroll
            for (int nt = 0; nt < 4; ++nt) {
                int row = nt * 16 + lr;
                int off = row * 256 + ((kk * 64 + lg * 16) ^ ((row & 7) << 4));
                bf16x8 kh = *reinterpret_cast<const bf16x8*>(KsB + off);
                bf16x8 kl = *reinterpret_cast<const bf16x8*>(KsB + 16384 + off);
                sc[nt] = __builtin_amdgcn_mfma_f32_16x16x32_bf16(qh[kk], kh, sc[nt], 0, 0, 0);
                sc[nt] = __builtin_amdgcn_mfma_f32_16x16x32_bf16(ql[kk], kh, sc[nt], 0, 0, 0);
                sc[nt] = __builtin_amdgcn_mfma_f32_16x16x32_bf16(qh[kk], kl, sc[nt], 0, 0, 0);
            }
        }
        __builtin_amdgcn_s_setprio(0);
        float mnew[4], alpha[4], psum[4];
#pragma unroll
        for (int r = 0; r < 4; ++r) {
            int row_t = t0 + w * 16 + lg * 4 + r;
            float mx = mrun[r];
#pragma unroll
            for (int nt = 0; nt < 4; ++nt) {
                int col = s0 + nt * 16 + lr;
                float v = sc[nt][r];
                if (col > row_t) v = -INFINITY;
                sc[nt][r] = v;
                mx = fmaxf(mx, v);
            }
#pragma unroll
            for (int o = 1; o < 16; o <<= 1) mx = fmaxf(mx, __shfl_xor(mx, o));
            mnew[r] = mx;
            alpha[r] = expf(mrun[r] - mx);
            mrun[r] = mx;
            psum[r] = 0.f;
        }
#pragma unroll
        for (int nt = 0; nt < 4; ++nt) {
#pragma unroll
            for (int r = 0; r < 4; ++r) {
                float p = expf(sc[nt][r] - mnew[r]);
                psum[r] += p;
                int prow = lg * 4 + r;
                int off = prow * 128 + (((nt * 16 + lr) * 2) ^ ((prow & 7) << 4));
                unsigned short ph = f2bf(p);
                *reinterpret_cast<unsigned short*>(PsB + off) = ph;
                *reinterpret_cast<unsigned short*>(PsB + 2048 + off) = f2bf(p - bf2f(ph));
            }
        }
#pragma unroll
        for (int r = 0; r < 4; ++r) {
            float s = psum[r];
#pragma unroll
            for (int o = 1; o < 16; o <<= 1) s += __shfl_xor(s, o);
            lrun[r] = lrun[r] * alpha[r] + s;
        }
#pragma unroll
        for (int dt = 0; dt < 8; ++dt)
#pragma unroll
            for (int r = 0; r < 4; ++r) oacc[dt][r] *= alpha[r];
        bf16x8 ph[2], pl[2];
#pragma unroll
        for (int kk = 0; kk < 2; ++kk) {
            int off = lr * 128 + ((kk * 64 + lg * 16) ^ ((lr & 7) << 4));
            ph[kk] = *reinterpret_cast<const bf16x8*>(PsB + off);
            pl[kk] = *reinterpret_cast<const bf16x8*>(PsB + 2048 + off);
        }
        __builtin_amdgcn_s_setprio(1);
#pragma unroll
        for (int dt = 0; dt < 8; ++dt) {
            int row = dt * 16 + lr;
#pragma unroll
            for (int kk = 0; kk < 2; ++kk) {
                int off = row * 128 + ((kk * 64 + lg * 16) ^ ((row & 7) << 4));
                bf16x8 vh = *reinterpret_cast<const bf16x8*>(VtB + off);
                bf16x8 vl = *reinterpret_cast<const bf16x8*>(VtB + 16384 + off);
                oacc[dt] = __builtin_amdgcn_mfma_f32_16x16x32_bf16(ph[kk], vh, oacc[dt], 0, 0, 0);
                oacc[dt] = __builtin_amdgcn_mfma_f32_16x16x32_bf16(ph[kk], vl, oacc[dt], 0, 0, 0);
                oacc[dt] = __builtin_amdgcn_mfma_f32_16x16x32_bf16(pl[kk], vh, oacc[dt], 0, 0, 0);
            }
        }
        __builtin_amdgcn_s_setprio(0);
        __syncthreads();
    }
#pragma unroll
    for (int r = 0; r < 4; ++r) {
        float inv = 1.f / lrun[r];
        int row_t = t0 + w * 16 + lg * 4 + r;
#pragma unroll
        for (int dt = 0; dt < 8; ++dt) {
            float o = oacc[dt][r] * inv;
            unsigned short hb = f2bf(o);
            size_t idx = (size_t)row_t * 2048 + h * 128 + dt * 16 + lr;
            oh[idx] = hb;
            ol[idx] = f2bf(o - bf2f(hb));
        }
    }
}

// ---------- residual add + RMSNorm (also emits bf16 plane for MoE A-staging) ----------
__global__ __launch_bounds__(256) void add_rmsnorm(const float* __restrict__ resid,
                                                   const float* __restrict__ x,
                                                   const float* __restrict__ w,
                                                   float* __restrict__ out,
                                                   unsigned short* __restrict__ outbf) {
    __shared__ float red[256];
    const int t = blockIdx.x, tid = threadIdx.x;
    const float* xr = x + (size_t)t * HID;
    float v[8];
    float s = 0.f;
#pragma unroll
    for (int i = 0; i < 8; ++i) { v[i] = xr[tid + i * 256]; s = fmaf(v[i], v[i], s); }
    float tot = block_reduce_sum_256(s, red);
    float scale = rsqrtf(tot * (1.f / HID) + EPSV);
#pragma unroll
    for (int i = 0; i < 8; ++i) {
        int d = tid + i * 256;
        float o = resid[(size_t)t * HID + d] + v[i] * scale * w[d];
        out[(size_t)t * HID + d] = o;
        outbf[(size_t)t * HID + d] = f2bf(o);
    }
}

// ---------- router ----------
__global__ __launch_bounds__(64) void router_kernel(const float* __restrict__ h1,
                                                    const float* __restrict__ gate_w,
                                                    int* __restrict__ topi, float* __restrict__ topv,
                                                    int* __restrict__ slot_tk, int* __restrict__ counts) {
    const int t = blockIdx.x, lane = threadIdx.x;
    float acc[NEXP] = {};
    const float* x = h1 + (size_t)t * HID;
    for (int d = lane; d < HID; d += 64) {
        float xv = x[d];
#pragma unroll
        for (int e = 0; e < NEXP; ++e) acc[e] = fmaf(xv, gate_w[e * HID + d], acc[e]);
    }
#pragma unroll
    for (int e = 0; e < NEXP; ++e)
#pragma unroll
        for (int off = 32; off > 0; off >>= 1) acc[e] += __shfl_down(acc[e], off);
    if (lane == 0) {
        float mx = acc[0];
        for (int e = 1; e < NEXP; ++e) mx = fmaxf(mx, acc[e]);
        float p[NEXP], se = 0.f;
        for (int e = 0; e < NEXP; ++e) { p[e] = expf(acc[e] - mx); se += p[e]; }
        float inv = 1.f / se;
        for (int e = 0; e < NEXP; ++e) p[e] *= inv;
        int e1 = 0;
        for (int e = 1; e < NEXP; ++e) if (p[e] > p[e1]) e1 = e;
        int e2 = (e1 == 0) ? 1 : 0;
        for (int e = 0; e < NEXP; ++e) if (e != e1 && p[e] > p[e2]) e2 = e;
        topi[t * 2] = e1;     topv[t * 2] = p[e1];
        topi[t * 2 + 1] = e2; topv[t * 2 + 1] = p[e2];
        slot_tk[t * 2]     = atomicAdd(&counts[e1], 1);
        slot_tk[t * 2 + 1] = atomicAdd(&counts[e2], 1);
    }
}

__global__ void scan_kernel(const int* __restrict__ counts, int* __restrict__ offs) {
    int o = 0;
    for (int e = 0; e < NEXP; ++e) { offs[e] = o; o += counts[e]; }
}

__global__ __launch_bounds__(256) void map_kernel(const int* __restrict__ topi,
                                                  const int* __restrict__ slot_tk,
                                                  const int* __restrict__ offs,
                                                  int* __restrict__ token_of_row,
                                                  int* __restrict__ row_of_tk) {
    int idx = blockIdx.x * 256 + threadIdx.x;
    if (idx >= TT * 2) return;
    int e = topi[idx];
    int row = offs[e] + slot_tk[idx];
    token_of_row[row] = idx >> 1;
    row_of_tk[idx] = row;
}

// ---------- final: combine top-2 expert outputs, RMSNorm, add residual ----------
__global__ __launch_bounds__(256) void final_combine(const float* __restrict__ h1,
                                                     const float* __restrict__ ypart,
                                                     const float* __restrict__ topv,
                                                     const int* __restrict__ row_of_tk,
                                                     const float* __restrict__ wffn,
                                                     float* __restrict__ out) {
    __shared__ float red[256];
    const int t = blockIdx.x, tid = threadIdx.x;
    const int r0 = row_of_tk[t * 2], r1 = row_of_tk[t * 2 + 1];
    const float w0 = topv[t * 2], w1 = topv[t * 2 + 1];
    const float* y0 = ypart + (size_t)r0 * HID;
    const float* y1 = ypart + (size_t)r1 * HID;
    float v[8];
    float s = 0.f;
#pragma unroll
    for (int i = 0; i < 8; ++i) {
        int d = tid + i * 256;
        v[i] = w0 * y0[d] + w1 * y1[d];
        s = fmaf(v[i], v[i], s);
    }
    float tot = block_reduce_sum_256(s, red);
    float scale = rsqrtf(tot * (1.f / HID) + EPSV);
#pragma unroll
    for (int i = 0; i < 8; ++i) {
        int d = tid + i * 256;
        out[(size_t)t * HID + d] = h1[(size_t)t * HID + d] + v[i] * scale * wffn[d];
    }
}

extern "C" void kernel_launch(void* const* d_in, const int* in_sizes, int n_in,
                              void* d_out, int out_size, void* d_ws, size_t ws_size,
                              hipStream_t stream) {
    const int*   positions = (const int*)d_in[0];
    const float* hidden    = (const float*)d_in[1];
    const float* qkv_w     = (const float*)d_in[2];
    const float* o_w       = (const float*)d_in[3];
    const float* q_norm_w  = (const float*)d_in[4];
    const float* k_norm_w  = (const float*)d_in[5];
    const float* post_attn = (const float*)d_in[6];
    const float* post_ffn  = (const float*)d_in[7];
    const float* gate_w    = (const float*)d_in[8];
    const float* w_gate    = (const float*)d_in[9];
    const float* w_up      = (const float*)d_in[10];
    const float* w_down    = (const float*)d_in[11];
    float* out = (float*)d_out;

    char* ws = (char*)d_ws;
    size_t off = 0;
    auto alloc = [&](size_t bytes) -> void* {
        void* p = ws + off;
        off += (bytes + 255) & ~(size_t)255;
        return p;
    };
    float*          qkvbuf = (float*)alloc((size_t)TT * 6144 * 4);             // 50.33 MB
    unsigned short* hidsp  = (unsigned short*)alloc((size_t)TT * HID * 2 * 2); // 16.78 MB (hi|lo)
    unsigned short* wsp    = (unsigned short*)alloc(((size_t)6144 * HID * 2 + (size_t)HID * HID * 2) * 2); // 67.11 MB
    float*          h1     = (float*)alloc((size_t)TT * HID * 4);              // 16.78 MB
    unsigned short* h1bf   = (unsigned short*)alloc((size_t)TT * HID * 2);     //  8.39 MB
    int*   topi   = (int*)alloc(TT * 2 * 4);
    float* topv   = (float*)alloc(TT * 2 * 4);
    int*   slot   = (int*)alloc(TT * 2 * 4);
    int*   rowtk  = (int*)alloc(TT * 2 * 4);
    int*   tokrow = (int*)alloc(TT * 2 * 4);
    int*   counts = (int*)alloc(8 * 4);
    int*   offsb  = (int*)alloc(8 * 4);
    if (off > ws_size) return;  // loud failure rather than corruption

    // plane pointers
    unsigned short* hid_hi   = hidsp;
    unsigned short* hid_lo   = hidsp + (size_t)TT * HID;
    unsigned short* attnO_hi = hid_hi;   // hid planes dead after qkv GEMM
    unsigned short* attnO_lo = hid_lo;
    unsigned short* qkvw_hi = wsp;
    unsigned short* qkvw_lo = wsp + (size_t)6144 * HID;
    unsigned short* ow_hi   = wsp + (size_t)2 * 6144 * HID;
    unsigned short* ow_lo   = ow_hi + (size_t)HID * HID;
    // vt/kt overlay qkv_w planes (dead after qkv GEMM)
    unsigned short* vtbuf   = wsp;
    unsigned short* ktbuf   = wsp + (size_t)TT * HID * 2;
    // time-aliased regions in qkvbuf (dead after attention):
    unsigned short* hinter = (unsigned short*)qkvbuf;                       // silu*u bf16 [4096x1024], 8.39 MB
    float*          oOut   = qkvbuf + (size_t)8192 * INTERD;                // o-proj out (offset 33.55 MB)
    float*          ypart  = oOut;                                          // down out [4096x2048], spans oOut+hidsp

    hipMemsetAsync(counts, 0, 8 * sizeof(int), stream);

    dim3 b256(256);
    // pre-split router-critical operands
    split_f32k<<<dim3(TT * HID / 4 / 256), b256, 0, stream>>>(hidden, hid_hi, hid_lo, TT * HID / 4);
    split_f32k<<<dim3(6144 * HID / 4 / 256), b256, 0, stream>>>(qkv_w, qkvw_hi, qkvw_lo, 6144 * HID / 4);
    split_f32k<<<dim3(HID * HID / 4 / 256), b256, 0, stream>>>(o_w, ow_hi, ow_lo, HID * HID / 4);
    // qkv = x @ qkv_w^T  (split precision, pipelined)
    gemm_sp<<<dim3(6144 / 128, TT / 128), b256, 0, stream>>>(hid_hi, hid_lo, qkvw_hi, qkvw_lo,
                                                             qkvbuf, 6144, HID, HID);
    // rmsnorm(q), rmsnorm(k), rope -> in-place hi/lo bf16
    qknorm_rope_split<<<dim3(TT), b256, 0, stream>>>(qkvbuf, q_norm_w, k_norm_w, positions);
    // K shuffle + V transpose into attention-LDS-mirrored layouts
    kvprep<<<dim3(32, NHEADS), b256, 0, stream>>>((const unsigned short*)qkvbuf, ktbuf, vtbuf);
    // split-precision attention -> attnO hi/lo planes
    attn_mfma<<<dim3(512), b256, 0, stream>>>((const unsigned short*)qkvbuf, ktbuf, vtbuf,
                                              attnO_hi, attnO_lo);
    // o proj (split precision, pipelined)
    gemm_sp<<<dim3(HID / 128, TT / 128), b256, 0, stream>>>(attnO_hi, attnO_lo, ow_hi, ow_lo,
                                                            oOut, HID, HID, HID);
    // h1 = hidden + rmsnorm(oOut)*w  (+ bf16 plane for MoE)
    add_rmsnorm<<<dim3(TT), b256, 0, stream>>>(hidden, oOut, post_attn, h1, h1bf);
    // router
    router_kernel<<<dim3(TT), dim3(64), 0, stream>>>(h1, gate_w, topi, topv, slot, counts);
    scan_kernel<<<1, 1, 0, stream>>>(counts, offsb);
    map_kernel<<<dim3((TT * 2 + 255) / 256), b256, 0, stream>>>(topi, slot, offsb, tokrow, rowtk);
    // expert FFN: fused gate+up (A staged once, silu fused -> bf16 hinter), then down
    gemm_gu<<<dim3(INTERD / 128, 32, NEXP), b256, 0, stream>>>(
        h1bf, w_gate, w_up, hinter, INTERD, HID, HID, (size_t)INTERD * HID, tokrow, offsb, counts);
    gemm_moe_down<<<dim3(HID / 128, 32, NEXP), b256, 0, stream>>>(
        hinter, w_down, ypart, HID, INTERD, INTERD, (size_t)HID * INTERD, offsb, counts);
    // out = h1 + rmsnorm(sum_k w_k * y_k)*w_ffn
    final_combine<<<dim3(TT), b256, 0, stream>>>(h1, ypart, topv, rowtk, post_ffn, out);
}

// Round 18
// 660.171 us; speedup vs baseline: 1.1103x; 1.1103x over previous
//
#include <hip/hip_runtime.h>
#include <hip/hip_bf16.h>
#include <cmath>

#define TT 2048
#define HID 2048
#define NHEADS 16
#define HDIM 128
#define NEXP 8
#define INTERD 1024
#define EPSV 1e-5f

typedef short bf16x8 __attribute__((ext_vector_type(8)));
typedef float f32x4 __attribute__((ext_vector_type(4)));

__device__ __forceinline__ unsigned short f2bf(float f) {
    unsigned int u = __builtin_bit_cast(unsigned int, f);
    unsigned int r = (u + 0x7FFFu + ((u >> 16) & 1u)) >> 16;
    return (unsigned short)r;
}
__device__ __forceinline__ float bf2f(unsigned short h) {
    return __builtin_bit_cast(float, (unsigned int)h << 16);
}

__device__ __forceinline__ void gll16(const void* g, void* l) {
    __builtin_amdgcn_global_load_lds((const __attribute__((address_space(1))) void*)g,
                                     (__attribute__((address_space(3))) void*)l, 16, 0, 0);
}

__device__ __forceinline__ float block_reduce_sum_256(float v, float* red) {
    const int tid = threadIdx.x;
    red[tid] = v;
    __syncthreads();
    for (int s = 128; s > 0; s >>= 1) {
        if (tid < s) red[tid] += red[tid + s];
        __syncthreads();
    }
    float r = red[0];
    __syncthreads();
    return r;
}

// ---------- f32 -> (hi, lo) bf16 planes ----------
__global__ __launch_bounds__(256) void split_f32k(const float* __restrict__ x,
                                                  unsigned short* __restrict__ hi,
                                                  unsigned short* __restrict__ lo, int n4) {
    int i = blockIdx.x * 256 + threadIdx.x;
    if (i >= n4) return;
    float4 v = reinterpret_cast<const float4*>(x)[i];
    float xs[4] = {v.x, v.y, v.z, v.w};
    unsigned short hs[4], ls[4];
#pragma unroll
    for (int u = 0; u < 4; ++u) {
        hs[u] = f2bf(xs[u]);
        ls[u] = f2bf(xs[u] - bf2f(hs[u]));
    }
    uint2 hp; hp.x = hs[0] | ((unsigned)hs[1] << 16); hp.y = hs[2] | ((unsigned)hs[3] << 16);
    uint2 lp; lp.x = ls[0] | ((unsigned)ls[1] << 16); lp.y = ls[2] | ((unsigned)ls[3] << 16);
    *reinterpret_cast<uint2*>(hi + (size_t)i * 4) = hp;
    *reinterpret_cast<uint2*>(lo + (size_t)i * 4) = lp;
}

// ===================== split-precision MFMA GEMM, pre-split operands, dbuf + counted vmcnt =========
#define GSTAGE(BUF, K0)                                                             \
    {                                                                               \
        char* base_ = (char*)Smem + (BUF) * 32768;                                  \
        _Pragma("unroll")                                                           \
        for (int i_ = 0; i_ < 2; ++i_) {                                            \
            int c_ = tid + i_ * 256;                                                \
            int r_ = c_ >> 2, s_ = c_ & 3;                                          \
            int ko_ = (K0) + (((s_ ^ ((r_ >> 1) & 3)) & 3) << 3);                   \
            gll16(Ah + (size_t)(m0 + r_) * lda + ko_, base_ + c_ * 16);             \
            gll16(Al + (size_t)(m0 + r_) * lda + ko_, base_ + 8192 + c_ * 16);      \
            gll16(Bh + (size_t)(n0 + r_) * K + ko_, base_ + 16384 + c_ * 16);       \
            gll16(Bl + (size_t)(n0 + r_) * K + ko_, base_ + 24576 + c_ * 16);       \
        }                                                                           \
    }

__global__ __launch_bounds__(256) void gemm_sp(const unsigned short* __restrict__ Ah,
                                               const unsigned short* __restrict__ Al,
                                               const unsigned short* __restrict__ Bh,
                                               const unsigned short* __restrict__ Bl,
                                               float* __restrict__ C, int N, int K, int lda) {
    // bijective XCD-aware block swizzle (T1)
    const int nbx = gridDim.x;
    const int nwg = nbx * gridDim.y;
    const int orig = blockIdx.y * nbx + blockIdx.x;
    const int qq = nwg >> 3, rr = nwg & 7;
    const int xcd = orig & 7, loc = orig >> 3;
    const int wgid = (xcd < rr ? xcd * (qq + 1) : rr * (qq + 1) + (xcd - rr) * qq) + loc;
    const int m0 = (wgid / nbx) * 128, n0 = (wgid % nbx) * 128;

    __shared__ __align__(16) unsigned short Smem[2 * 4 * 128 * 32];  // 64 KB
    const int tid = threadIdx.x;
    const int w = tid >> 6, l = tid & 63;
    const int lr = l & 15, lg = l >> 4;
    const int wm = w >> 1, wn = w & 1;

    f32x4 acc[4][4];
#pragma unroll
    for (int i = 0; i < 4; ++i)
#pragma unroll
        for (int j = 0; j < 4; ++j) acc[i][j] = f32x4{0.f, 0.f, 0.f, 0.f};

    const int nks = K >> 5;
    GSTAGE(0, 0);
    int cur = 0;
    for (int ks = 0; ks < nks; ++ks) {
        if (ks + 1 < nks) {
            GSTAGE(cur ^ 1, (ks + 1) << 5);
            asm volatile("s_waitcnt vmcnt(8)" ::: "memory");
        } else {
            asm volatile("s_waitcnt vmcnt(0)" ::: "memory");
        }
        __builtin_amdgcn_s_barrier();
        __builtin_amdgcn_sched_barrier(0);
        char* bb = (char*)Smem + cur * 32768;
        bf16x8 bhf[4], blf[4];
#pragma unroll
        for (int nt = 0; nt < 4; ++nt) {
            int row = wn * 64 + nt * 16 + lr;
            int off = row * 64 + (((lg ^ ((row >> 1) & 3)) & 3) << 4);
            bhf[nt] = *reinterpret_cast<const bf16x8*>(bb + 16384 + off);
            blf[nt] = *reinterpret_cast<const bf16x8*>(bb + 24576 + off);
        }
        __builtin_amdgcn_s_setprio(1);
#pragma unroll
        for (int mt = 0; mt < 4; ++mt) {
            int row = wm * 64 + mt * 16 + lr;
            int off = row * 64 + (((lg ^ ((row >> 1) & 3)) & 3) << 4);
            bf16x8 ahf = *reinterpret_cast<const bf16x8*>(bb + off);
            bf16x8 alf = *reinterpret_cast<const bf16x8*>(bb + 8192 + off);
#pragma unroll
            for (int nt = 0; nt < 4; ++nt) {
                acc[mt][nt] = __builtin_amdgcn_mfma_f32_16x16x32_bf16(ahf, bhf[nt], acc[mt][nt], 0, 0, 0);
                acc[mt][nt] = __builtin_amdgcn_mfma_f32_16x16x32_bf16(ahf, blf[nt], acc[mt][nt], 0, 0, 0);
                acc[mt][nt] = __builtin_amdgcn_mfma_f32_16x16x32_bf16(alf, bhf[nt], acc[mt][nt], 0, 0, 0);
            }
        }
        __builtin_amdgcn_s_setprio(0);
        asm volatile("s_waitcnt lgkmcnt(0)" ::: "memory");
        __builtin_amdgcn_s_barrier();
        __builtin_amdgcn_sched_barrier(0);
        cur ^= 1;
    }
#pragma unroll
    for (int mt = 0; mt < 4; ++mt) {
#pragma unroll
        for (int r = 0; r < 4; ++r) {
            size_t crow = (size_t)(m0 + wm * 64 + mt * 16 + lg * 4 + r) * N;
#pragma unroll
            for (int nt = 0; nt < 4; ++nt)
                C[crow + n0 + wn * 64 + nt * 16 + lr] = acc[mt][nt][r];
        }
    }
}

// ===================== MoE MFMA GEMM, BM=64 tiles (2-4x active blocks vs BM=128) ====================
// Tile 64x128, 4 waves 2x2 (each 32 rows x 64 cols). ABF: A bf16; else f32 stage-convert.
// MODE 1: silu(gsrc)*acc -> bf16 out. MODE 0: f32 out.
template<int ABF, int MODE>
__global__ __launch_bounds__(256) void gemm_moe(const void* __restrict__ Ap,
                                                const float* __restrict__ B,
                                                void* __restrict__ Cout,
                                                const float* __restrict__ gsrc,
                                                int N, int K, int lda,
                                                size_t strideB,
                                                const int* __restrict__ gather,
                                                const int* __restrict__ offs,
                                                const int* __restrict__ counts) {
    const int e = blockIdx.z;
    const int cnt = counts[e];
    const int base = offs[e];
    const int m0 = blockIdx.y * 64;
    if (m0 >= cnt) return;
    const int n0 = blockIdx.x * 128;
    const float* Bp = B + (size_t)e * strideB;

    __shared__ unsigned short smA[64 * 64];    // 8 KB
    __shared__ unsigned short smB[128 * 64];   // 16 KB
    __shared__ int rowsA[64];
    const int tid = threadIdx.x;
    if (tid < 64) {
        int rr = min(m0 + tid, cnt - 1);
        rowsA[tid] = gather ? gather[base + rr] : (base + rr);
    }
    __syncthreads();

    const int w = tid >> 6, l = tid & 63;
    const int lr = l & 15, lg = l >> 4;
    const int wm = w >> 1, wn = w & 1;
    char* sA = (char*)smA;
    char* sB = (char*)smB;

    f32x4 acc[2][4];
#pragma unroll
    for (int i = 0; i < 2; ++i)
#pragma unroll
        for (int j = 0; j < 4; ++j) acc[i][j] = f32x4{0.f, 0.f, 0.f, 0.f};

    for (int k0 = 0; k0 < K; k0 += 64) {
        if (ABF) {
            // A bf16: 64 rows x 8 chunks of 16B = 512 slots, 2/thread
            const unsigned short* Abf = (const unsigned short*)Ap;
#pragma unroll
            for (int i = 0; i < 2; ++i) {
                int slot = tid + i * 256;
                int r = slot >> 3, sg = slot & 7;
                uint4 v = *reinterpret_cast<const uint4*>(&Abf[(size_t)rowsA[r] * lda + k0 + sg * 8]);
                *reinterpret_cast<uint4*>(sA + r * 128 + ((sg * 16) ^ ((r & 7) << 4))) = v;
            }
        } else {
            // A f32 stage-convert: 64 rows x 16 quads = 1024 slots, 4/thread
            const float* Af = (const float*)Ap;
#pragma unroll
            for (int i = 0; i < 4; ++i) {
                int slot = tid + i * 256;
                int r = slot >> 4, kq = slot & 15;
                float4 av = *reinterpret_cast<const float4*>(&Af[(size_t)rowsA[r] * lda + k0 + kq * 4]);
                uint2 pk;
                pk.x = (unsigned)f2bf(av.x) | ((unsigned)f2bf(av.y) << 16);
                pk.y = (unsigned)f2bf(av.z) | ((unsigned)f2bf(av.w) << 16);
                *reinterpret_cast<uint2*>(sA + r * 128 + ((kq * 8) ^ ((r & 7) << 4))) = pk;
            }
        }
        // B f32 stage-convert: 128 rows x 16 quads = 2048 slots, 8/thread
#pragma unroll
        for (int i = 0; i < 8; ++i) {
            int slot = tid + i * 256;
            int r = slot >> 4, kq = slot & 15;
            float4 bv = *reinterpret_cast<const float4*>(&Bp[(size_t)(n0 + r) * K + k0 + kq * 4]);
            uint2 pk;
            pk.x = (unsigned)f2bf(bv.x) | ((unsigned)f2bf(bv.y) << 16);
            pk.y = (unsigned)f2bf(bv.z) | ((unsigned)f2bf(bv.w) << 16);
            *reinterpret_cast<uint2*>(sB + r * 128 + ((kq * 8) ^ ((r & 7) << 4))) = pk;
        }
        __syncthreads();
#pragma unroll
        for (int kk = 0; kk < 2; ++kk) {
            bf16x8 af[2], bfr[4];
#pragma unroll
            for (int mt = 0; mt < 2; ++mt) {
                int row = wm * 32 + mt * 16 + lr;
                af[mt] = *reinterpret_cast<const bf16x8*>(sA + row * 128 + ((kk * 64 + lg * 16) ^ ((row & 7) << 4)));
            }
#pragma unroll
            for (int nt = 0; nt < 4; ++nt) {
                int row = wn * 64 + nt * 16 + lr;
                bfr[nt] = *reinterpret_cast<const bf16x8*>(sB + row * 128 + ((kk * 64 + lg * 16) ^ ((row & 7) << 4)));
            }
            __builtin_amdgcn_s_setprio(1);
#pragma unroll
            for (int mt = 0; mt < 2; ++mt)
#pragma unroll
                for (int nt = 0; nt < 4; ++nt)
                    acc[mt][nt] = __builtin_amdgcn_mfma_f32_16x16x32_bf16(af[mt], bfr[nt], acc[mt][nt], 0, 0, 0);
            __builtin_amdgcn_s_setprio(0);
        }
        __syncthreads();
    }
#pragma unroll
    for (int mt = 0; mt < 2; ++mt) {
#pragma unroll
        for (int r = 0; r < 4; ++r) {
            int rowl = wm * 32 + mt * 16 + lg * 4 + r;
            if (m0 + rowl < cnt) {
                size_t crow = (size_t)(base + m0 + rowl) * N;
#pragma unroll
                for (int nt = 0; nt < 4; ++nt) {
                    size_t idx = crow + n0 + wn * 64 + nt * 16 + lr;
                    if (MODE == 1) {
                        float g = gsrc[idx];
                        ((unsigned short*)Cout)[idx] = f2bf(g / (1.f + expf(-g)) * acc[mt][nt][r]);
                    } else {
                        ((float*)Cout)[idx] = acc[mt][nt][r];
                    }
                }
            }
        }
    }
}

// ===================== flat-2048 RMSNorm + NeoX RoPE -> in-place hi/lo bf16 split =====================
__global__ __launch_bounds__(256) void qknorm_rope_split(float* __restrict__ qkv,
                                                         const float* __restrict__ qw,
                                                         const float* __restrict__ kw,
                                                         const int* __restrict__ pos) {
    __shared__ float xbuf[2048];
    __shared__ float red[256];
    const int t = blockIdx.x, tid = threadIdx.x;
    unsigned short* row16 = (unsigned short*)(qkv + (size_t)t * 6144);
    const float pf = (float)pos[t];
    float vreg[8];
    const float* vsrc = qkv + (size_t)t * 6144 + 4096;
#pragma unroll
    for (int i = 0; i < 8; ++i) vreg[i] = vsrc[tid + i * 256];
    __syncthreads();
#pragma unroll
    for (int i = 0; i < 8; ++i) {
        int d = tid + i * 256;
        unsigned short hi = f2bf(vreg[i]);
        row16[8192 + d] = hi;
        row16[10240 + d] = f2bf(vreg[i] - bf2f(hi));
    }
    for (int part = 0; part < 2; ++part) {
        const float* x = qkv + (size_t)t * 6144 + part * 2048;
        const float* wn = part ? kw : qw;
        const int sbase = part ? 4096 : 0;
        const float outscale = part ? 1.0f : 0.08838834764831845f;
        float s = 0.f;
#pragma unroll
        for (int i = 0; i < 8; ++i) {
            int d = tid + i * 256;
            float v = x[d];
            xbuf[d] = v;
            s = fmaf(v, v, s);
        }
        float tot = block_reduce_sum_256(s, red);
        float scale = rsqrtf(tot * (1.f / HID) + EPSV);
#pragma unroll
        for (int p = tid; p < 1024; p += 256) {
            int hh = p >> 6, j = p & 63;
            int i1 = hh * 128 + j, i2 = i1 + 64;
            float x1 = xbuf[i1] * scale * wn[i1];
            float x2 = xbuf[i2] * scale * wn[i2];
            float invf = expf(-(float)j * 0.14391156831212787f);
            float ang = pf * invf;
            float sn, cs;
            sincosf(ang, &sn, &cs);
            float o1 = (x1 * cs - x2 * sn) * outscale;
            float o2 = (x2 * cs + x1 * sn) * outscale;
            unsigned short h1_ = f2bf(o1);
            row16[sbase + i1] = h1_;
            row16[sbase + 2048 + i1] = f2bf(o1 - bf2f(h1_));
            unsigned short h2_ = f2bf(o2);
            row16[sbase + i2] = h2_;
            row16[sbase + 2048 + i2] = f2bf(o2 - bf2f(h2_));
        }
        __syncthreads();
    }
}

// ===================== K/V prep: per (head, chunk) blocks, LDS-image layouts =====================
__global__ __launch_bounds__(256) void kvprep(const unsigned short* __restrict__ qkv16,
                                              unsigned short* __restrict__ kt,
                                              unsigned short* __restrict__ vt) {
    const int C = blockIdx.x;
    const int h = blockIdx.y;
    const int tid = threadIdx.x;
#pragma unroll
    for (int p = 0; p < 2; ++p) {
#pragma unroll
        for (int i = 0; i < 4; ++i) {
            int slot = tid + i * 256;
            int r = slot >> 4, sg = slot & 15;
            uint4 v = *reinterpret_cast<const uint4*>(
                qkv16 + (size_t)(C * 64 + r) * 12288 + 4096 + p * 2048 + h * 128 + (sg ^ (r & 7)) * 8);
            *reinterpret_cast<uint4*>(kt + (size_t)(h * 32 + C) * 16384 + p * 8192 + slot * 8) = v;
        }
    }
    __shared__ unsigned short tile[64 * 128];
    char* tb = (char*)tile;
    for (int p = 0; p < 2; ++p) {
#pragma unroll
        for (int i = 0; i < 4; ++i) {
            int c = tid + i * 256;
            int r = c >> 4, dseg = c & 15;
            uint4 v = *reinterpret_cast<const uint4*>(
                qkv16 + (size_t)(C * 64 + r) * 12288 + 8192 + p * 2048 + h * 128 + dseg * 8);
            int swz = dseg ^ (r & 7) ^ (r >> 3);
            *reinterpret_cast<uint4*>(tb + r * 256 + swz * 16) = v;
        }
        __syncthreads();
        unsigned short* ob = vt + (size_t)(h * 32 + C) * 16384 + p * 8192;
#pragma unroll
        for (int i = 0; i < 4; ++i) {
            int c = tid + i * 256;
            int d = c >> 3, j = c & 7;
            unsigned short tmp[8];
#pragma unroll
            for (int u = 0; u < 8; ++u) {
                int s = 8 * j + u;
                int swz = (d >> 3) ^ (s & 7) ^ (s >> 3);
                tmp[u] = *reinterpret_cast<const unsigned short*>(tb + s * 256 + swz * 16 + (d & 7) * 2);
            }
            *reinterpret_cast<uint4*>(ob + (size_t)d * 64 + ((j ^ (d & 7)) * 8)) =
                *reinterpret_cast<const uint4*>(tmp);
        }
        __syncthreads();
    }
}

// stage one 64-key chunk (K hi/lo + V hi/lo = 64KB) direct to LDS: 16 x global_load_lds
#define STAGE1(CIDX)                                                                   \
    {                                                                                  \
        const unsigned short* kb_ = kt + (size_t)(h * 32 + (CIDX)) * 16384;            \
        const unsigned short* vb_ = vt + (size_t)(h * 32 + (CIDX)) * 16384;            \
        _Pragma("unroll")                                                              \
        for (int p_ = 0; p_ < 2; ++p_) {                                               \
            _Pragma("unroll")                                                          \
            for (int i_ = 0; i_ < 4; ++i_) {                                           \
                int slot_ = tid + i_ * 256;                                            \
                gll16(kb_ + p_ * 8192 + slot_ * 8, kvb + p_ * 16384 + slot_ * 16);     \
                gll16(vb_ + p_ * 8192 + slot_ * 8, kvb + 32768 + p_ * 16384 + slot_ * 16); \
            }                                                                          \
        }                                                                              \
    }

// ===================== split-precision MFMA flash attention (80KB LDS -> 2 blocks/CU) ==============
__global__ __launch_bounds__(256) void attn_mfma(const unsigned short* __restrict__ qkv16,
                                                 const unsigned short* __restrict__ kt,
                                                 const unsigned short* __restrict__ vt,
                                                 unsigned short* __restrict__ oh,
                                                 unsigned short* __restrict__ ol) {
    const int g = blockIdx.x;
    const int rank = (g < 256) ? g : 767 - g;
    const int h = rank & 15;
    const int t0 = (31 - (rank >> 4)) * 64;
    const int tid = threadIdx.x;
    const int w = tid >> 6, l = tid & 63;
    const int lr = l & 15, lg = l >> 4;
    const size_t RS = 12288;
    __shared__ __align__(16) unsigned short KVs[32768];
    __shared__ unsigned short Ps[4][2 * 16 * 64];
    char* kvb = (char*)KVs;
    char* PsB = (char*)(Ps[w]);

    bf16x8 qh[4], ql[4];
    {
        const unsigned short* qp = qkv16 + (size_t)(t0 + w * 16 + lr) * RS + h * 128 + lg * 8;
#pragma unroll
        for (int kk = 0; kk < 4; ++kk) {
            qh[kk] = *reinterpret_cast<const bf16x8*>(qp + kk * 32);
            ql[kk] = *reinterpret_cast<const bf16x8*>(qp + 2048 + kk * 32);
        }
    }
    f32x4 oacc[8];
#pragma unroll
    for (int dt = 0; dt < 8; ++dt) oacc[dt] = f32x4{0.f, 0.f, 0.f, 0.f};
    float mrun[4] = {-INFINITY, -INFINITY, -INFINITY, -INFINITY};
    float lrun[4] = {0.f, 0.f, 0.f, 0.f};

    for (int s0 = 0; s0 <= t0; s0 += 64) {
        STAGE1(s0 >> 6);
        __syncthreads();
        char* KsB = kvb;
        char* VtB = kvb + 32768;

        f32x4 sc[4];
#pragma unroll
        for (int nt = 0; nt < 4; ++nt) sc[nt] = f32x4{0.f, 0.f, 0.f, 0.f};
        __builtin_amdgcn_s_setprio(1);
#pragma unroll
        for (int kk = 0; kk < 4; ++kk) {
#pragma unroll
            for (int nt = 0; nt < 4; ++nt) {
                int row = nt * 16 + lr;
                int off = row * 256 + ((kk * 64 + lg * 16) ^ ((row & 7) << 4));
                bf16x8 kh = *reinterpret_cast<const bf16x8*>(KsB + off);
                bf16x8 kl = *reinterpret_cast<const bf16x8*>(KsB + 16384 + off);
                sc[nt] = __builtin_amdgcn_mfma_f32_16x16x32_bf16(qh[kk], kh, sc[nt], 0, 0, 0);
                sc[nt] = __builtin_amdgcn_mfma_f32_16x16x32_bf16(ql[kk], kh, sc[nt], 0, 0, 0);
                sc[nt] = __builtin_amdgcn_mfma_f32_16x16x32_bf16(qh[kk], kl, sc[nt], 0, 0, 0);
            }
        }
        __builtin_amdgcn_s_setprio(0);
        float mnew[4], alpha[4], psum[4];
#pragma unroll
        for (int r = 0; r < 4; ++r) {
            int row_t = t0 + w * 16 + lg * 4 + r;
            float mx = mrun[r];
#pragma unroll
            for (int nt = 0; nt < 4; ++nt) {
                int col = s0 + nt * 16 + lr;
                float v = sc[nt][r];
                if (col > row_t) v = -INFINITY;
                sc[nt][r] = v;
                mx = fmaxf(mx, v);
            }
#pragma unroll
            for (int o = 1; o < 16; o <<= 1) mx = fmaxf(mx, __shfl_xor(mx, o));
            mnew[r] = mx;
            alpha[r] = expf(mrun[r] - mx);
            mrun[r] = mx;
            psum[r] = 0.f;
        }
#pragma unroll
        for (int nt = 0; nt < 4; ++nt) {
#pragma unroll
            for (int r = 0; r < 4; ++r) {
                float p = expf(sc[nt][r] - mnew[r]);
                psum[r] += p;
                int prow = lg * 4 + r;
                int off = prow * 128 + (((nt * 16 + lr) * 2) ^ ((prow & 7) << 4));
                unsigned short ph = f2bf(p);
                *reinterpret_cast<unsigned short*>(PsB + off) = ph;
                *reinterpret_cast<unsigned short*>(PsB + 2048 + off) = f2bf(p - bf2f(ph));
            }
        }
#pragma unroll
        for (int r = 0; r < 4; ++r) {
            float s = psum[r];
#pragma unroll
            for (int o = 1; o < 16; o <<= 1) s += __shfl_xor(s, o);
            lrun[r] = lrun[r] * alpha[r] + s;
        }
#pragma unroll
        for (int dt = 0; dt < 8; ++dt)
#pragma unroll
            for (int r = 0; r < 4; ++r) oacc[dt][r] *= alpha[r];
        bf16x8 ph[2], pl[2];
#pragma unroll
        for (int kk = 0; kk < 2; ++kk) {
            int off = lr * 128 + ((kk * 64 + lg * 16) ^ ((lr & 7) << 4));
            ph[kk] = *reinterpret_cast<const bf16x8*>(PsB + off);
            pl[kk] = *reinterpret_cast<const bf16x8*>(PsB + 2048 + off);
        }
        __builtin_amdgcn_s_setprio(1);
#pragma unroll
        for (int dt = 0; dt < 8; ++dt) {
            int row = dt * 16 + lr;
#pragma unroll
            for (int kk = 0; kk < 2; ++kk) {
                int off = row * 128 + ((kk * 64 + lg * 16) ^ ((row & 7) << 4));
                bf16x8 vh = *reinterpret_cast<const bf16x8*>(VtB + off);
                bf16x8 vl = *reinterpret_cast<const bf16x8*>(VtB + 16384 + off);
                oacc[dt] = __builtin_amdgcn_mfma_f32_16x16x32_bf16(ph[kk], vh, oacc[dt], 0, 0, 0);
                oacc[dt] = __builtin_amdgcn_mfma_f32_16x16x32_bf16(ph[kk], vl, oacc[dt], 0, 0, 0);
                oacc[dt] = __builtin_amdgcn_mfma_f32_16x16x32_bf16(pl[kk], vh, oacc[dt], 0, 0, 0);
            }
        }
        __builtin_amdgcn_s_setprio(0);
        __syncthreads();
    }
#pragma unroll
    for (int r = 0; r < 4; ++r) {
        float inv = 1.f / lrun[r];
        int row_t = t0 + w * 16 + lg * 4 + r;
#pragma unroll
        for (int dt = 0; dt < 8; ++dt) {
            float o = oacc[dt][r] * inv;
            unsigned short hb = f2bf(o);
            size_t idx = (size_t)row_t * 2048 + h * 128 + dt * 16 + lr;
            oh[idx] = hb;
            ol[idx] = f2bf(o - bf2f(hb));
        }
    }
}

// ---------- residual add + RMSNorm (also emits bf16 plane for MoE A-staging) ----------
__global__ __launch_bounds__(256) void add_rmsnorm(const float* __restrict__ resid,
                                                   const float* __restrict__ x,
                                                   const float* __restrict__ w,
                                                   float* __restrict__ out,
                                                   unsigned short* __restrict__ outbf) {
    __shared__ float red[256];
    const int t = blockIdx.x, tid = threadIdx.x;
    const float* xr = x + (size_t)t * HID;
    float v[8];
    float s = 0.f;
#pragma unroll
    for (int i = 0; i < 8; ++i) { v[i] = xr[tid + i * 256]; s = fmaf(v[i], v[i], s); }
    float tot = block_reduce_sum_256(s, red);
    float scale = rsqrtf(tot * (1.f / HID) + EPSV);
#pragma unroll
    for (int i = 0; i < 8; ++i) {
        int d = tid + i * 256;
        float o = resid[(size_t)t * HID + d] + v[i] * scale * w[d];
        out[(size_t)t * HID + d] = o;
        outbf[(size_t)t * HID + d] = f2bf(o);
    }
}

// ---------- router ----------
__global__ __launch_bounds__(64) void router_kernel(const float* __restrict__ h1,
                                                    const float* __restrict__ gate_w,
                                                    int* __restrict__ topi, float* __restrict__ topv,
                                                    int* __restrict__ slot_tk, int* __restrict__ counts) {
    const int t = blockIdx.x, lane = threadIdx.x;
    float acc[NEXP] = {};
    const float* x = h1 + (size_t)t * HID;
    for (int d = lane; d < HID; d += 64) {
        float xv = x[d];
#pragma unroll
        for (int e = 0; e < NEXP; ++e) acc[e] = fmaf(xv, gate_w[e * HID + d], acc[e]);
    }
#pragma unroll
    for (int e = 0; e < NEXP; ++e)
#pragma unroll
        for (int off = 32; off > 0; off >>= 1) acc[e] += __shfl_down(acc[e], off);
    if (lane == 0) {
        float mx = acc[0];
        for (int e = 1; e < NEXP; ++e) mx = fmaxf(mx, acc[e]);
        float p[NEXP], se = 0.f;
        for (int e = 0; e < NEXP; ++e) { p[e] = expf(acc[e] - mx); se += p[e]; }
        float inv = 1.f / se;
        for (int e = 0; e < NEXP; ++e) p[e] *= inv;
        int e1 = 0;
        for (int e = 1; e < NEXP; ++e) if (p[e] > p[e1]) e1 = e;
        int e2 = (e1 == 0) ? 1 : 0;
        for (int e = 0; e < NEXP; ++e) if (e != e1 && p[e] > p[e2]) e2 = e;
        topi[t * 2] = e1;     topv[t * 2] = p[e1];
        topi[t * 2 + 1] = e2; topv[t * 2 + 1] = p[e2];
        slot_tk[t * 2]     = atomicAdd(&counts[e1], 1);
        slot_tk[t * 2 + 1] = atomicAdd(&counts[e2], 1);
    }
}

__global__ void scan_kernel(const int* __restrict__ counts, int* __restrict__ offs) {
    int o = 0;
    for (int e = 0; e < NEXP; ++e) { offs[e] = o; o += counts[e]; }
}

__global__ __launch_bounds__(256) void map_kernel(const int* __restrict__ topi,
                                                  const int* __restrict__ slot_tk,
                                                  const int* __restrict__ offs,
                                                  int* __restrict__ token_of_row,
                                                  int* __restrict__ row_of_tk) {
    int idx = blockIdx.x * 256 + threadIdx.x;
    if (idx >= TT * 2) return;
    int e = topi[idx];
    int row = offs[e] + slot_tk[idx];
    token_of_row[row] = idx >> 1;
    row_of_tk[idx] = row;
}

// ---------- final: combine top-2 expert outputs, RMSNorm, add residual ----------
__global__ __launch_bounds__(256) void final_combine(const float* __restrict__ h1,
                                                     const float* __restrict__ ypart,
                                                     const float* __restrict__ topv,
                                                     const int* __restrict__ row_of_tk,
                                                     const float* __restrict__ wffn,
                                                     float* __restrict__ out) {
    __shared__ float red[256];
    const int t = blockIdx.x, tid = threadIdx.x;
    const int r0 = row_of_tk[t * 2], r1 = row_of_tk[t * 2 + 1];
    const float w0 = topv[t * 2], w1 = topv[t * 2 + 1];
    const float* y0 = ypart + (size_t)r0 * HID;
    const float* y1 = ypart + (size_t)r1 * HID;
    float v[8];
    float s = 0.f;
#pragma unroll
    for (int i = 0; i < 8; ++i) {
        int d = tid + i * 256;
        v[i] = w0 * y0[d] + w1 * y1[d];
        s = fmaf(v[i], v[i], s);
    }
    float tot = block_reduce_sum_256(s, red);
    float scale = rsqrtf(tot * (1.f / HID) + EPSV);
#pragma unroll
    for (int i = 0; i < 8; ++i) {
        int d = tid + i * 256;
        out[(size_t)t * HID + d] = h1[(size_t)t * HID + d] + v[i] * scale * wffn[d];
    }
}

extern "C" void kernel_launch(void* const* d_in, const int* in_sizes, int n_in,
                              void* d_out, int out_size, void* d_ws, size_t ws_size,
                              hipStream_t stream) {
    const int*   positions = (const int*)d_in[0];
    const float* hidden    = (const float*)d_in[1];
    const float* qkv_w     = (const float*)d_in[2];
    const float* o_w       = (const float*)d_in[3];
    const float* q_norm_w  = (const float*)d_in[4];
    const float* k_norm_w  = (const float*)d_in[5];
    const float* post_attn = (const float*)d_in[6];
    const float* post_ffn  = (const float*)d_in[7];
    const float* gate_w    = (const float*)d_in[8];
    const float* w_gate    = (const float*)d_in[9];
    const float* w_up      = (const float*)d_in[10];
    const float* w_down    = (const float*)d_in[11];
    float* out = (float*)d_out;

    char* ws = (char*)d_ws;
    size_t off = 0;
    auto alloc = [&](size_t bytes) -> void* {
        void* p = ws + off;
        off += (bytes + 255) & ~(size_t)255;
        return p;
    };
    float*          qkvbuf = (float*)alloc((size_t)TT * 6144 * 4);             // 50.33 MB
    unsigned short* hidsp  = (unsigned short*)alloc((size_t)TT * HID * 2 * 2); // 16.78 MB (hi|lo)
    unsigned short* wsp    = (unsigned short*)alloc(((size_t)6144 * HID * 2 + (size_t)HID * HID * 2) * 2); // 67.11 MB
    float*          h1     = (float*)alloc((size_t)TT * HID * 4);              // 16.78 MB
    unsigned short* h1bf   = (unsigned short*)alloc((size_t)TT * HID * 2);     //  8.39 MB
    int*   topi   = (int*)alloc(TT * 2 * 4);
    float* topv   = (float*)alloc(TT * 2 * 4);
    int*   slot   = (int*)alloc(TT * 2 * 4);
    int*   rowtk  = (int*)alloc(TT * 2 * 4);
    int*   tokrow = (int*)alloc(TT * 2 * 4);
    int*   counts = (int*)alloc(8 * 4);
    int*   offsb  = (int*)alloc(8 * 4);
    if (off > ws_size) return;  // loud failure rather than corruption

    // plane pointers
    unsigned short* hid_hi   = hidsp;
    unsigned short* hid_lo   = hidsp + (size_t)TT * HID;
    unsigned short* attnO_hi = hid_hi;   // hid planes dead after qkv GEMM
    unsigned short* attnO_lo = hid_lo;
    unsigned short* qkvw_hi = wsp;
    unsigned short* qkvw_lo = wsp + (size_t)6144 * HID;
    unsigned short* ow_hi   = wsp + (size_t)2 * 6144 * HID;
    unsigned short* ow_lo   = ow_hi + (size_t)HID * HID;
    // vt/kt overlay qkv_w planes (dead after qkv GEMM)
    unsigned short* vtbuf   = wsp;
    unsigned short* ktbuf   = wsp + (size_t)TT * HID * 2;
    // time-aliased regions in qkvbuf (dead after attention):
    unsigned short* hinter = (unsigned short*)qkvbuf;                       // silu*u bf16 [4096x1024], [0, 8.39)
    float*          gbuf   = qkvbuf + (size_t)4096 * INTERD;                // gate out f32 [4096x1024], [16.78, 33.55)
    float*          oOut   = qkvbuf + (size_t)8192 * INTERD;                // o-proj out, [33.55, 50.33)
    float*          ypart  = oOut;                                          // down out [4096x2048], spans oOut+hidsp

    hipMemsetAsync(counts, 0, 8 * sizeof(int), stream);

    dim3 b256(256);
    // pre-split router-critical operands
    split_f32k<<<dim3(TT * HID / 4 / 256), b256, 0, stream>>>(hidden, hid_hi, hid_lo, TT * HID / 4);
    split_f32k<<<dim3(6144 * HID / 4 / 256), b256, 0, stream>>>(qkv_w, qkvw_hi, qkvw_lo, 6144 * HID / 4);
    split_f32k<<<dim3(HID * HID / 4 / 256), b256, 0, stream>>>(o_w, ow_hi, ow_lo, HID * HID / 4);
    // qkv = x @ qkv_w^T  (split precision, pipelined)
    gemm_sp<<<dim3(6144 / 128, TT / 128), b256, 0, stream>>>(hid_hi, hid_lo, qkvw_hi, qkvw_lo,
                                                             qkvbuf, 6144, HID, HID);
    // rmsnorm(q), rmsnorm(k), rope -> in-place hi/lo bf16
    qknorm_rope_split<<<dim3(TT), b256, 0, stream>>>(qkvbuf, q_norm_w, k_norm_w, positions);
    // K shuffle + V transpose into attention-LDS-mirrored layouts
    kvprep<<<dim3(32, NHEADS), b256, 0, stream>>>((const unsigned short*)qkvbuf, ktbuf, vtbuf);
    // split-precision attention -> attnO hi/lo planes
    attn_mfma<<<dim3(512), b256, 0, stream>>>((const unsigned short*)qkvbuf, ktbuf, vtbuf,
                                              attnO_hi, attnO_lo);
    // o proj (split precision, pipelined)
    gemm_sp<<<dim3(HID / 128, TT / 128), b256, 0, stream>>>(attnO_hi, attnO_lo, ow_hi, ow_lo,
                                                            oOut, HID, HID, HID);
    // h1 = hidden + rmsnorm(oOut)*w  (+ bf16 plane for MoE)
    add_rmsnorm<<<dim3(TT), b256, 0, stream>>>(hidden, oOut, post_attn, h1, h1bf);
    // router
    router_kernel<<<dim3(TT), dim3(64), 0, stream>>>(h1, gate_w, topi, topv, slot, counts);
    scan_kernel<<<1, 1, 0, stream>>>(counts, offsb);
    map_kernel<<<dim3((TT * 2 + 255) / 256), b256, 0, stream>>>(topi, slot, offsb, tokrow, rowtk);
    // expert FFN, BM=64 tiles: gate (bf16 A gather) -> gbuf f32; up (fused silu) -> bf16 hinter;
    //                          down (bf16 A packed) -> ypart f32
    gemm_moe<1, 0><<<dim3(INTERD / 128, TT * 2 / 64, NEXP), b256, 0, stream>>>(
        h1bf, w_gate, gbuf, nullptr, INTERD, HID, HID, (size_t)INTERD * HID, tokrow, offsb, counts);
    gemm_moe<1, 1><<<dim3(INTERD / 128, TT * 2 / 64, NEXP), b256, 0, stream>>>(
        h1bf, w_up, hinter, gbuf, INTERD, HID, HID, (size_t)INTERD * HID, tokrow, offsb, counts);
    gemm_moe<1, 0><<<dim3(HID / 128, TT * 2 / 64, NEXP), b256, 0, stream>>>(
        hinter, w_down, ypart, nullptr, HID, INTERD, INTERD, (size_t)HID * INTERD, nullptr, offsb, counts);
    // out = h1 + rmsnorm(sum_k w_k * y_k)*w_ffn
    final_combine<<<dim3(TT), b256, 0, stream>>>(h1, ypart, topv, rowtk, post_ffn, out);
}